// Round 15
// baseline (796.221 us; speedup 1.0000x reference)
//
#include <hip/hip_runtime.h>
#include <stdint.h>

#define N_NODES 50000
#define N_EDGES 400000
#define M_PAD   50048   // 391 * 128

typedef __attribute__((ext_vector_type(8))) __bf16 bf16x8;
typedef __attribute__((ext_vector_type(4))) float floatx4;

__device__ __forceinline__ unsigned short f2bf(float f) {
    unsigned int u = __float_as_uint(f);
    unsigned int r = (u + 0x7fffu + ((u >> 16) & 1u)) >> 16;
    return (unsigned short)r;
}

__device__ __forceinline__ float bf2f(unsigned short u) {
    return __uint_as_float(((unsigned int)u) << 16);
}

__device__ __forceinline__ void gload_lds16(const void* g, void* l) {
    __builtin_amdgcn_global_load_lds((__attribute__((address_space(1))) void*)g,
                                     (__attribute__((address_space(3))) void*)l,
                                     16, 0, 0);
}

// ---------------- fused: x->bf16 conv  ||  W^T build  ||  dst histogram ----------------
__global__ void k_pre(const float* __restrict__ x, unsigned short* __restrict__ xb,
                      const float* __restrict__ Wq, const float* __restrict__ Wk,
                      const float* __restrict__ Wv, const float* __restrict__ Ws,
                      const float* __restrict__ bq, const float* __restrict__ bk,
                      const float* __restrict__ bv, const float* __restrict__ bs,
                      unsigned short* __restrict__ WT, float* __restrict__ biascat,
                      const int* __restrict__ ei, int* __restrict__ cnt) {
    int bid = blockIdx.x;
    if (bid < 4096) {
        // conv_x: fp32 -> bf16, padded to M_PAD rows
        const int total = M_PAD * 256;  // float4 units
        for (int u = bid * 256 + threadIdx.x; u < total; u += 4096 * 256) {
            int row = u >> 8;
            int c4  = u & 255;
            float4 v = make_float4(0.f, 0.f, 0.f, 0.f);
            if (row < N_NODES) v = ((const float4*)x)[(size_t)row * 256 + c4];
            ushort4 o;
            o.x = f2bf(v.x); o.y = f2bf(v.y); o.z = f2bf(v.z); o.w = f2bf(v.w);
            ((ushort4*)xb)[u] = o;
        }
    } else if (bid < 8192) {
        // build W^T (bf16, [ncol=1024][k=1024]) + bias concat
        int idx = (bid - 4096) * 256 + threadIdx.x;   // 0 .. 1M-1
        int n = idx >> 10;
        int k = idx & 1023;
        int g = n >> 8, d = n & 255;
        const float* W = (g == 0) ? Wq : (g == 1) ? Wk : (g == 2) ? Wv : Ws;
        WT[idx] = f2bf(W[k * 256 + d]);
        if (idx < 1024) {
            int g2 = idx >> 8, d2 = idx & 255;
            const float* B = (g2 == 0) ? bq : (g2 == 1) ? bk : (g2 == 2) ? bv : bs;
            biascat[idx] = B[d2];
        }
    } else {
        // histogram of dst
        int e = (bid - 8192) * 256 + threadIdx.x;
        if (e < N_EDGES) atomicAdd(&cnt[ei[N_EDGES + e]], 1);
    }
}

// ---------------- CSR build: exclusive prefix scan (single block, 256 thr) ----------------
__global__ void k_scan(const int* __restrict__ cnt, int* __restrict__ offs) {
    __shared__ int wsums[4];
    const int CH = 196;  // 256*196 = 50176 >= 50000
    int t = threadIdx.x;
    int beg = t * CH;
    int end = beg + CH; if (end > N_NODES) end = N_NODES;
    int s = 0;
    for (int i = beg; i < end; i++) s += cnt[i];
    // inclusive wave scan
    int lane = t & 63, w = t >> 6;
    int v = s;
#pragma unroll
    for (int off = 1; off < 64; off <<= 1) {
        int u = __shfl_up(v, off, 64);
        if (lane >= off) v += u;
    }
    if (lane == 63) wsums[w] = v;
    __syncthreads();
    int carry = 0;
    for (int i = 0; i < w; i++) carry += wsums[i];
    int run = carry + v - s;  // exclusive prefix for this thread's chunk
    for (int i = beg; i < end; i++) {
        offs[i] = run;
        run += cnt[i];
    }
    if (t == 255) offs[N_NODES] = run;  // == N_EDGES
}

// ---------------- bf16 MFMA GEMM + fused CSR scatter (independent block ranges) ----------
// Blocks 0..3135: 2-phase-derived GEMM body, now with:
//   (T4) counted-vmcnt double buffer: compute(buf) -> barrier -> STAGE(buf, kt+2) ->
//        vmcnt(4) -> barrier. At the vmcnt(4): 8 loads outstanding (tile kt+1 issued a
//        full K-step ago + tile kt+2 just issued); waits only kt+1's 4 oldest -> near-
//        zero stall. No vmcnt(0) in steady state. Barrier-after-compute makes the
//        buffer overwrite safe (stage issued after all waves finished reading).
//   (T2) granule XOR-swizzle g ^= (row>>1)&3, applied on the GLOBAL source during
//        global_load_lds (LDS dest stays linear, rule 21) and on the read offset.
//        Old layout: lanes {0,2,..,14} same bank quad = 8-way conflict (1.28e7
//        measured). New: 2-way (free). Both sides reduce to per-thread constants.
// Blocks 3136..4698: CSR scatter (independent; returns before any barrier).
__launch_bounds__(256)
__global__ void k_gemm(const unsigned short* __restrict__ A,
                       const unsigned short* __restrict__ BT,
                       const float* __restrict__ bias,
                       float* __restrict__ qbuf, unsigned short* __restrict__ kvb,
                       float* __restrict__ sbuf,
                       const int* __restrict__ ei, const int* __restrict__ offs,
                       int* __restrict__ fill, int* __restrict__ ssrc) {
    __shared__ unsigned short As[2 * 4096];   // 2 bufs x 128rows x 32k bf16 = 16 KB
    __shared__ unsigned short Bs[2 * 4096];   // 16 KB

    int wg = blockIdx.x;
    if (wg >= 3136) {
        // ---- fused scatter: e = (wg-3136)*256 + tid ----
        int e = (wg - 3136) * 256 + threadIdx.x;
        if (e < N_EDGES) {
            int src = ei[e];
            int dst = ei[N_EDGES + e];
            int pos = offs[dst] + atomicAdd(&fill[dst], 1);
            ssrc[pos] = src;
        }
        return;
    }

    // ---- XCD swizzle: wg -> (row strip yt, col tile xt); 3136 = 8 xcd * 392 ----
    int xcd  = wg & 7;
    int j    = wg >> 3;             // 0..391
    int xt   = j & 7;
    int ygrp = j >> 3;              // 0..48
    int yt   = ygrp * 8 + xcd;
    if (yt >= 391) return;          // uniform early-exit (before any barrier)

    const int row0 = yt * 128;
    const int col0 = xt * 128;

    const int t = threadIdx.x;
    const int w = t >> 6;
    const int l = t & 63;

    const int lr = l >> 2;          // stage row within 16-row wave chunk
    // stage-side source granule: dest granule (l&3) XOR swizzle s(row)=(lr>>1)&3=(l>>3)&3
    const int lcg = ((l & 3) ^ ((l >> 3) & 3)) * 8;

    const int wr = (w >> 1) * 64;
    const int wc = (w & 1) * 64;
    const int lane15 = l & 15;
    const int quad = l >> 4;
    // read-side swizzled granule: quad XOR s(row)=((lane15)>>1)&3 (wr, i*16 are 0 mod 4 after >>1)
    const int qx = quad ^ ((lane15 >> 1) & 3);

    floatx4 acc[4][4];
#pragma unroll
    for (int i = 0; i < 4; i++)
#pragma unroll
        for (int j2 = 0; j2 < 4; j2++) acc[i][j2] = (floatx4)0.f;

#define STAGE(buf, ktn)                                                                   \
    {                                                                                     \
        const int kko = (ktn) * 32;                                                       \
        _Pragma("unroll")                                                                 \
        for (int issue = 0; issue < 2; issue++) {                                         \
            int arow = row0 + issue * 64 + w * 16 + lr;                                   \
            gload_lds16(A + (size_t)arow * 1024 + kko + lcg,                              \
                        As + (buf) * 4096 + issue * 2048 + w * 512);                      \
            int brow = col0 + issue * 64 + w * 16 + lr;                                   \
            gload_lds16(BT + (size_t)brow * 1024 + kko + lcg,                             \
                        Bs + (buf) * 4096 + issue * 2048 + w * 512);                      \
        }                                                                                 \
    }

#define COMPUTE(buf)                                                                      \
    {                                                                                     \
        const unsigned short* Ab = As + (buf) * 4096;                                     \
        const unsigned short* Bb = Bs + (buf) * 4096;                                     \
        bf16x8 af[4], bfr[4];                                                             \
        _Pragma("unroll")                                                                 \
        for (int i = 0; i < 4; i++) {                                                     \
            af[i]  = *(const bf16x8*)(Ab + (wr + i * 16 + lane15) * 32 + qx * 8);         \
            bfr[i] = *(const bf16x8*)(Bb + (wc + i * 16 + lane15) * 32 + qx * 8);         \
        }                                                                                 \
        _Pragma("unroll")                                                                 \
        for (int i = 0; i < 4; i++)                                                       \
            _Pragma("unroll")                                                             \
            for (int j2 = 0; j2 < 4; j2++)                                                \
                acc[i][j2] = __builtin_amdgcn_mfma_f32_16x16x32_bf16(af[i], bfr[j2],      \
                                                                    acc[i][j2], 0, 0, 0);\
    }

    // prologue: tiles 0,1 staged (8 loads out); vmcnt(4) -> tile0's 4 oldest landed
    STAGE(0, 0);
    STAGE(1, 1);
    __builtin_amdgcn_s_waitcnt(0x0f74);  // vmcnt(4)
    __syncthreads();

    for (int kt = 0; kt < 32; kt += 2) {
        COMPUTE(0);                      // tile kt
        __syncthreads();                 // all waves done reading buf0
        if (kt + 2 < 32) {
            STAGE(0, kt + 2);            // overwrite freed buf0
            __builtin_amdgcn_s_waitcnt(0x0f74);  // vmcnt(4): tile kt+1 landed
        } else {
            __builtin_amdgcn_s_waitcnt(0x0f70);  // vmcnt(0): tile 31 landed
        }
        __syncthreads();

        COMPUTE(1);                      // tile kt+1
        if (kt + 1 < 31) {
            __syncthreads();             // all waves done reading buf1
            STAGE(1, kt + 3);            // overwrite freed buf1
            __builtin_amdgcn_s_waitcnt(0x0f74);  // vmcnt(4): tile kt+2 landed
            __syncthreads();
        }
    }

#undef STAGE
#undef COMPUTE

#pragma unroll
    for (int i = 0; i < 4; i++) {
#pragma unroll
        for (int j2 = 0; j2 < 4; j2++) {
            int col = col0 + wc + j2 * 16 + lane15;
            int g = col >> 8;          // uniform per fragment (16-col span within group)
            int d = col & 255;
            float bcol = bias[col];
#pragma unroll
            for (int r = 0; r < 4; r++) {
                int row = row0 + wr + i * 16 + quad * 4 + r;
                float val = acc[i][j2][r] + bcol;
                if (g == 0)      qbuf[(size_t)row * 256 + d] = val;
                else if (g == 1) kvb[(size_t)row * 512 + d] = f2bf(val);
                else if (g == 2) kvb[(size_t)row * 512 + 256 + d] = f2bf(val);
                else             sbuf[(size_t)row * 256 + d] = val;
            }
        }
    }
}

// ---------------- attention gather, BLOCK per node: 4 waves stripe the edge list --------
// Wave w handles edges w, w+4, w+8, ... of its node -> 4x the loads in flight vs
// wave-per-node (round-9 was latency-bound at 889 GB/s; this measured ~93us round-10).
// Partial (acc,den) per wave -> 5KB LDS reduce -> wave 0 runs gelu+gate tail.
// Softmax without max-subtraction (same math as all verified rounds).
__launch_bounds__(256)
__global__ void k_attn(const int* __restrict__ offs, const int* __restrict__ ssrc,
                       const float* __restrict__ qbuf, const unsigned short* __restrict__ kvb,
                       const float* __restrict__ sbuf,
                       const float* __restrict__ gate_w, const float* __restrict__ gate_b,
                       float* __restrict__ out_h, float* __restrict__ exsc) {
    __shared__ float4 lacc[4][64];
    __shared__ float  lden[4][64];
    int w = threadIdx.x >> 6, l = threadIdx.x & 63;
    int n = blockIdx.x;             // grid = exactly N_NODES blocks

    float4 qv = ((const float4*)(qbuf + (size_t)n * 256))[l];  // dims 4l..4l+3, head = l>>4
    int beg = offs[n], end = offs[n + 1];

    float4 acc = make_float4(0.f, 0.f, 0.f, 0.f);
    float den = 0.f;

    for (int base = beg; base < end; base += 256) {
        int m = end - base; if (m > 256) m = 256;
        int eIdx = w + 4 * l;                         // this wave+lane's edge slot
        int mysrc = (eIdx < m) ? ssrc[base + eIdx] : 0;
        int nIter = (m > w) ? ((m - w + 3) >> 2) : 0; // edges w, w+4, ... < m
        for (int jj = 0; jj < nIter; jj++) {
            int src = __shfl(mysrc, jj, 64);
            const unsigned short* row = kvb + (size_t)src * 512;
            ushort4 ku = ((const ushort4*)row)[l];          // k dims 4l..4l+3
            ushort4 vu = ((const ushort4*)(row + 256))[l];  // v dims 4l..4l+3
            float p = qv.x * bf2f(ku.x) + qv.y * bf2f(ku.y) +
                      qv.z * bf2f(ku.z) + qv.w * bf2f(ku.w);
            p += __shfl_xor(p, 1, 16);
            p += __shfl_xor(p, 2, 16);
            p += __shfl_xor(p, 4, 16);
            p += __shfl_xor(p, 8, 16);           // all 16 lanes of a head hold s
            float ex = expf(p * 0.125f);
            den += ex;
            acc.x += ex * bf2f(vu.x); acc.y += ex * bf2f(vu.y);
            acc.z += ex * bf2f(vu.z); acc.w += ex * bf2f(vu.w);
        }
    }

    lacc[w][l] = acc;
    lden[w][l] = den;
    __syncthreads();
    if (w != 0) return;

    float4 a0 = lacc[0][l], a1 = lacc[1][l], a2 = lacc[2][l], a3 = lacc[3][l];
    acc.x = a0.x + a1.x + a2.x + a3.x;
    acc.y = a0.y + a1.y + a2.y + a3.y;
    acc.z = a0.z + a1.z + a2.z + a3.z;
    acc.w = a0.w + a1.w + a2.w + a3.w;
    den = lden[0][l] + lden[1][l] + lden[2][l] + lden[3][l];

    float inv = (den > 0.f) ? 1.f / den : 0.f;     // deg-0 node -> agg = 0 (matches ref)
    float4 sk = ((const float4*)(sbuf + (size_t)n * 256))[l];

    float z0 = acc.x * inv + sk.x;
    float z1 = acc.y * inv + sk.y;
    float z2 = acc.z * inv + sk.z;
    float z3 = acc.w * inv + sk.w;

    const float is2 = 0.70710678118f;
    float h0 = 0.5f * z0 * (1.f + erff(z0 * is2));
    float h1 = 0.5f * z1 * (1.f + erff(z1 * is2));
    float h2 = 0.5f * z2 * (1.f + erff(z2 * is2));
    float h3 = 0.5f * z3 * (1.f + erff(z3 * is2));
    ((float4*)(out_h + (size_t)n * 256))[l] = make_float4(h0, h1, h2, h3);

    int d0 = l * 4;
    float s0 = h0 * gate_w[(d0 + 0) * 2] + h1 * gate_w[(d0 + 1) * 2] +
               h2 * gate_w[(d0 + 2) * 2] + h3 * gate_w[(d0 + 3) * 2];
    float s1 = h0 * gate_w[(d0 + 0) * 2 + 1] + h1 * gate_w[(d0 + 1) * 2 + 1] +
               h2 * gate_w[(d0 + 2) * 2 + 1] + h3 * gate_w[(d0 + 3) * 2 + 1];
#pragma unroll
    for (int off = 1; off < 64; off <<= 1) {
        s0 += __shfl_xor(s0, off, 64);
        s1 += __shfl_xor(s1, off, 64);
    }
    if (l == 0) {
        exsc[n * 2 + 0] = expf(s0 + gate_b[0]);
        exsc[n * 2 + 1] = expf(s1 + gate_b[1]);
    }
}

// ---------------- esum[c] = sum_n exsc[n,c] ----------------
__global__ void k_esum(const float* __restrict__ exsc, float* __restrict__ esum) {
    __shared__ float red0[4], red1[4];
    float p0 = 0.f, p1 = 0.f;
    for (int n = blockIdx.x * blockDim.x + threadIdx.x; n < N_NODES; n += gridDim.x * blockDim.x) {
        p0 += exsc[n * 2];
        p1 += exsc[n * 2 + 1];
    }
#pragma unroll
    for (int off = 1; off < 64; off <<= 1) {
        p0 += __shfl_xor(p0, off, 64);
        p1 += __shfl_xor(p1, off, 64);
    }
    int w = threadIdx.x >> 6, l = threadIdx.x & 63;
    if (l == 0) { red0[w] = p0; red1[w] = p1; }
    __syncthreads();
    if (threadIdx.x == 0) {
        atomicAdd(&esum[0], red0[0] + red0[1] + red0[2] + red0[3]);
        atomicAdd(&esum[1], red1[0] + red1[1] + red1[2] + red1[3]);
    }
}

// ---------------- attn/A outputs (fp32) + t[c,d] = sum_n attn[n,c] h[n,d] ----------------
__global__ void k_t(const float* __restrict__ exsc, const float* __restrict__ esum,
                    const float* __restrict__ h_f, const int* __restrict__ label_p,
                    float* __restrict__ attn_out, float* __restrict__ A_out,
                    float* __restrict__ t_ws) {
    int d = threadIdx.x;
    float inv0 = 1.f / esum[0], inv1 = 1.f / esum[1];
    int lab = *label_p;
    int n0 = blockIdx.x * 98;
    int n1 = n0 + 98; if (n1 > N_NODES) n1 = N_NODES;
    float t0 = 0.f, t1 = 0.f;
    for (int n = n0; n < n1; n++) {
        float e0 = exsc[n * 2], e1 = exsc[n * 2 + 1];
        float a0 = e0 * inv0, a1 = e1 * inv1;
        float hv = h_f[(size_t)n * 256 + d];
        t0 += a0 * hv;
        t1 += a1 * hv;
        if (d == 0) attn_out[n * 2] = a0;
        else if (d == 1) attn_out[n * 2 + 1] = a1;
        else if (d == 2) A_out[n] = (lab == 0) ? a0 : a1;
    }
    atomicAdd(&t_ws[d], t0);
    atomicAdd(&t_ws[256 + d], t1);
}

// ---------------- y = t @ pool_w + pool_b (fp32 out) ----------------
__global__ void k_y(const float* __restrict__ t_ws, const float* __restrict__ pool_w,
                    const float* __restrict__ pool_b, float* __restrict__ y_out) {
    int d = threadIdx.x;
    float a0 = pool_b[d], a1 = pool_b[d];
    for (int k = 0; k < 256; k++) {
        float w = pool_w[k * 256 + d];
        a0 += t_ws[k] * w;
        a1 += t_ws[256 + k] * w;
    }
    y_out[d] = a0;
    y_out[256 + d] = a1;
}

extern "C" void kernel_launch(void* const* d_in, const int* in_sizes, int n_in,
                              void* d_out, int out_size, void* d_ws, size_t ws_size,
                              hipStream_t stream) {
    const float* x      = (const float*)d_in[0];
    const int*   ei     = (const int*)d_in[1];
    const int*   label  = (const int*)d_in[2];
    const float* Wq     = (const float*)d_in[3];
    const float* bq     = (const float*)d_in[4];
    const float* Wk     = (const float*)d_in[5];
    const float* bk     = (const float*)d_in[6];
    const float* Wv     = (const float*)d_in[7];
    const float* bv     = (const float*)d_in[8];
    const float* Wskip  = (const float*)d_in[9];
    const float* bskip  = (const float*)d_in[10];
    const float* gate_w = (const float*)d_in[11];
    const float* gate_b = (const float*)d_in[12];
    const float* pool_w = (const float*)d_in[13];
    const float* pool_b = (const float*)d_in[14];

    char* ws = (char*)d_ws;
    size_t off = 0;
    float* qbuf = (float*)(ws + off);                 off += (size_t)M_PAD * 256 * 4;    // 51.25 MB
    unsigned short* kvb = (unsigned short*)(ws + off);off += (size_t)M_PAD * 512 * 2;    // 51.25 MB
    float* sbuf = (float*)(ws + off);                 off += (size_t)M_PAD * 256 * 4;    // 51.25 MB
    unsigned short* xb = (unsigned short*)(ws + off); off += (size_t)M_PAD * 1024 * 2;   // 102.5 MB
    unsigned short* WT = (unsigned short*)(ws + off); off += (size_t)1024 * 1024 * 2;    // 2 MB
    float* biascat = (float*)(ws + off);              off += 1024 * 4;
    int* cnt  = (int*)(ws + off);                     off += (size_t)N_NODES * 4;        // 200 KB
    int* fill = (int*)(ws + off);                     off += (size_t)N_NODES * 4;        // 200 KB (contig w/ cnt)
    int* offs = (int*)(ws + off);                     off += (size_t)(N_NODES + 1) * 4;
    int* ssrc = (int*)(ws + off);                     off += (size_t)N_EDGES * 4;        // 1.6 MB
    float* exsc = (float*)(ws + off);                 off += (size_t)N_NODES * 2 * 4;    // 0.4 MB
    float* esum = (float*)(ws + off);                 off += 2 * 4;
    float* t_ws = (float*)(ws + off);                 off += 512 * 4;

    // Outputs are FP32, concatenated flat in return order.
    float* out = (float*)d_out;
    float* y_out    = out;                 // 512
    float* attn_out = out + 512;           // 100000
    float* h_out    = out + 100512;        // 12800000
    float* A_out    = out + 12900512;      // 50000

    // zero cnt+fill (contiguous) and esum+t_ws (contiguous)
    hipMemsetAsync(cnt, 0, (size_t)N_NODES * 2 * 4, stream);
    hipMemsetAsync(esum, 0, (2 + 512) * 4, stream);

    // fused: conv_x (blocks 0..4095) | build_w (4096..8191) | hist (8192..9754)
    k_pre<<<9755, 256, 0, stream>>>(x, xb, Wq, Wk, Wv, Wskip, bq, bk, bv, bskip,
                                    WT, biascat, ei, cnt);
    k_scan<<<1, 256, 0, stream>>>(cnt, offs);
    // GEMM blocks 0..3135 (8 xcd * 392, yt-guard) + scatter blocks 3136..4698
    k_gemm<<<4699, 256, 0, stream>>>(xb, WT, biascat, qbuf, kvb, sbuf,
                                     ei, offs, fill, ssrc);
    k_attn<<<N_NODES, 256, 0, stream>>>(offs, ssrc, qbuf, kvb, sbuf, gate_w, gate_b,
                                        h_out, exsc);
    k_esum<<<128, 256, 0, stream>>>(exsc, esum);
    k_t<<<512, 256, 0, stream>>>(exsc, esum, h_out, label, attn_out, A_out, t_ws);
    k_y<<<1, 256, 0, stream>>>(t_ws, pool_w, pool_b, y_out);
}

// Round 20
// 754.592 us; speedup vs baseline: 1.0552x; 1.0552x over previous
//
#include <hip/hip_runtime.h>
#include <stdint.h>

#define N_NODES 50000
#define N_EDGES 400000
#define M_PAD   50048   // 391 * 128

typedef __attribute__((ext_vector_type(8))) __bf16 bf16x8;
typedef __attribute__((ext_vector_type(4))) float floatx4;

__device__ __forceinline__ unsigned short f2bf(float f) {
    unsigned int u = __float_as_uint(f);
    unsigned int r = (u + 0x7fffu + ((u >> 16) & 1u)) >> 16;
    return (unsigned short)r;
}

__device__ __forceinline__ float bf2f(unsigned short u) {
    return __uint_as_float(((unsigned int)u) << 16);
}

__device__ __forceinline__ void gload_lds16(const void* g, void* l) {
    __builtin_amdgcn_global_load_lds((__attribute__((address_space(1))) void*)g,
                                     (__attribute__((address_space(3))) void*)l,
                                     16, 0, 0);
}

// ---------------- fused: x->bf16 conv  ||  W^T build  ||  dst histogram ----------------
__global__ void k_pre(const float* __restrict__ x, unsigned short* __restrict__ xb,
                      const float* __restrict__ Wq, const float* __restrict__ Wk,
                      const float* __restrict__ Wv, const float* __restrict__ Ws,
                      const float* __restrict__ bq, const float* __restrict__ bk,
                      const float* __restrict__ bv, const float* __restrict__ bs,
                      unsigned short* __restrict__ WT, float* __restrict__ biascat,
                      const int* __restrict__ ei, int* __restrict__ cnt) {
    int bid = blockIdx.x;
    if (bid < 4096) {
        // conv_x: fp32 -> bf16, padded to M_PAD rows
        const int total = M_PAD * 256;  // float4 units
        for (int u = bid * 256 + threadIdx.x; u < total; u += 4096 * 256) {
            int row = u >> 8;
            int c4  = u & 255;
            float4 v = make_float4(0.f, 0.f, 0.f, 0.f);
            if (row < N_NODES) v = ((const float4*)x)[(size_t)row * 256 + c4];
            ushort4 o;
            o.x = f2bf(v.x); o.y = f2bf(v.y); o.z = f2bf(v.z); o.w = f2bf(v.w);
            ((ushort4*)xb)[u] = o;
        }
    } else if (bid < 8192) {
        // build W^T (bf16, [ncol=1024][k=1024]) + bias concat
        int idx = (bid - 4096) * 256 + threadIdx.x;   // 0 .. 1M-1
        int n = idx >> 10;
        int k = idx & 1023;
        int g = n >> 8, d = n & 255;
        const float* W = (g == 0) ? Wq : (g == 1) ? Wk : (g == 2) ? Wv : Ws;
        WT[idx] = f2bf(W[k * 256 + d]);
        if (idx < 1024) {
            int g2 = idx >> 8, d2 = idx & 255;
            const float* B = (g2 == 0) ? bq : (g2 == 1) ? bk : (g2 == 2) ? bv : bs;
            biascat[idx] = B[d2];
        }
    } else {
        // histogram of dst
        int e = (bid - 8192) * 256 + threadIdx.x;
        if (e < N_EDGES) atomicAdd(&cnt[ei[N_EDGES + e]], 1);
    }
}

// ---------------- CSR build: exclusive prefix scan (single block, 256 thr) ----------------
__global__ void k_scan(const int* __restrict__ cnt, int* __restrict__ offs) {
    __shared__ int wsums[4];
    const int CH = 196;  // 256*196 = 50176 >= 50000
    int t = threadIdx.x;
    int beg = t * CH;
    int end = beg + CH; if (end > N_NODES) end = N_NODES;
    int s = 0;
    for (int i = beg; i < end; i++) s += cnt[i];
    // inclusive wave scan
    int lane = t & 63, w = t >> 6;
    int v = s;
#pragma unroll
    for (int off = 1; off < 64; off <<= 1) {
        int u = __shfl_up(v, off, 64);
        if (lane >= off) v += u;
    }
    if (lane == 63) wsums[w] = v;
    __syncthreads();
    int carry = 0;
    for (int i = 0; i < w; i++) carry += wsums[i];
    int run = carry + v - s;  // exclusive prefix for this thread's chunk
    for (int i = beg; i < end; i++) {
        offs[i] = run;
        run += cnt[i];
    }
    if (t == 255) offs[N_NODES] = run;  // == N_EDGES
}

// ---------------- bf16 MFMA GEMM + fused CSR scatter (independent block ranges) ----------
// Blocks 0..3135: round-12 verified single-buffer 2-phase body (190us, occupancy 29%)
// + the round-15-verified granule XOR-swizzle ONLY (bank conflicts 1.28e7 -> 0,
// refcheck'd; instruction-count-neutral). Round-15's counted-vmcnt schedule reverted:
// it cost occupancy (29->21%, SGPR 112, LDS 32KB) and regressed 190->232 — the 2-phase
// drain is hidden by cross-block overlap, so conflicts/drain are off the critical path.
// Epilogue splits C: q->qbuf f32 | k,v->kvb bf16 | skip->sbuf f32.
// Blocks 3136..4698: CSR scatter (independent; returns before any barrier).
__launch_bounds__(256)
__global__ void k_gemm(const unsigned short* __restrict__ A,
                       const unsigned short* __restrict__ BT,
                       const float* __restrict__ bias,
                       float* __restrict__ qbuf, unsigned short* __restrict__ kvb,
                       float* __restrict__ sbuf,
                       const int* __restrict__ ei, const int* __restrict__ offs,
                       int* __restrict__ fill, int* __restrict__ ssrc) {
    __shared__ unsigned short As[128 * 32];
    __shared__ unsigned short Bs[128 * 32];

    int wg = blockIdx.x;
    if (wg >= 3136) {
        // ---- fused scatter: e = (wg-3136)*256 + tid ----
        int e = (wg - 3136) * 256 + threadIdx.x;
        if (e < N_EDGES) {
            int src = ei[e];
            int dst = ei[N_EDGES + e];
            int pos = offs[dst] + atomicAdd(&fill[dst], 1);
            ssrc[pos] = src;
        }
        return;
    }

    // ---- XCD swizzle: wg -> (row strip yt, col tile xt); 3136 = 8 xcd * 392 ----
    int xcd  = wg & 7;
    int j    = wg >> 3;             // 0..391
    int xt   = j & 7;
    int ygrp = j >> 3;              // 0..48
    int yt   = ygrp * 8 + xcd;
    if (yt >= 391) return;          // uniform early-exit (before any barrier)

    const int row0 = yt * 128;
    const int col0 = xt * 128;

    const int t = threadIdx.x;
    const int w = t >> 6;
    const int l = t & 63;

    const int lr = l >> 2;          // stage row within 16-row wave chunk
    // stage-side source granule: dest granule (l&3) XOR s(row)=(lr>>1)&3=(l>>3)&3
    const int lcg = ((l & 3) ^ ((l >> 3) & 3)) * 8;

    const int wr = (w >> 1) * 64;
    const int wc = (w & 1) * 64;
    const int lane15 = l & 15;
    const int quad = l >> 4;
    // read-side swizzled granule: quad XOR s(row)=((lane15)>>1)&3
    const int qx = quad ^ ((lane15 >> 1) & 3);

    floatx4 acc[4][4];
#pragma unroll
    for (int i = 0; i < 4; i++)
#pragma unroll
        for (int j2 = 0; j2 < 4; j2++) acc[i][j2] = (floatx4)0.f;

    for (int kk = 0; kk < 1024; kk += 32) {
        __syncthreads();
#pragma unroll
        for (int issue = 0; issue < 2; issue++) {
            int arow = row0 + issue * 64 + w * 16 + lr;
            gload_lds16(A + (size_t)arow * 1024 + kk + lcg, As + issue * 2048 + w * 512);
            int brow = col0 + issue * 64 + w * 16 + lr;
            gload_lds16(BT + (size_t)brow * 1024 + kk + lcg, Bs + issue * 2048 + w * 512);
        }
        __builtin_amdgcn_s_waitcnt(0x0f70);  // vmcnt(0)
        __syncthreads();

        bf16x8 af[4], bfr[4];
#pragma unroll
        for (int i = 0; i < 4; i++) {
            af[i]  = *(const bf16x8*)(As + (wr + i * 16 + lane15) * 32 + qx * 8);
            bfr[i] = *(const bf16x8*)(Bs + (wc + i * 16 + lane15) * 32 + qx * 8);
        }
#pragma unroll
        for (int i = 0; i < 4; i++)
#pragma unroll
            for (int j2 = 0; j2 < 4; j2++)
                acc[i][j2] = __builtin_amdgcn_mfma_f32_16x16x32_bf16(af[i], bfr[j2], acc[i][j2], 0, 0, 0);
    }

#pragma unroll
    for (int i = 0; i < 4; i++) {
#pragma unroll
        for (int j2 = 0; j2 < 4; j2++) {
            int col = col0 + wc + j2 * 16 + lane15;
            int g = col >> 8;          // uniform per fragment (16-col span within group)
            int d = col & 255;
            float bcol = bias[col];
#pragma unroll
            for (int r = 0; r < 4; r++) {
                int row = row0 + wr + i * 16 + quad * 4 + r;
                float val = acc[i][j2][r] + bcol;
                if (g == 0)      qbuf[(size_t)row * 256 + d] = val;
                else if (g == 1) kvb[(size_t)row * 512 + d] = f2bf(val);
                else if (g == 2) kvb[(size_t)row * 512 + 256 + d] = f2bf(val);
                else             sbuf[(size_t)row * 256 + d] = val;
            }
        }
    }
}

// ---------------- attention gather, BLOCK per node: 4 waves stripe the edge list --------
// Wave w handles edges w, w+4, w+8, ... of its node -> 4x the loads in flight vs
// wave-per-node (round-9 was latency-bound at 889 GB/s; this measured ~93us round-10).
// Partial (acc,den) per wave -> 5KB LDS reduce -> wave 0 runs gelu+gate tail.
// Softmax without max-subtraction (same math as all verified rounds).
__launch_bounds__(256)
__global__ void k_attn(const int* __restrict__ offs, const int* __restrict__ ssrc,
                       const float* __restrict__ qbuf, const unsigned short* __restrict__ kvb,
                       const float* __restrict__ sbuf,
                       const float* __restrict__ gate_w, const float* __restrict__ gate_b,
                       float* __restrict__ out_h, float* __restrict__ exsc) {
    __shared__ float4 lacc[4][64];
    __shared__ float  lden[4][64];
    int w = threadIdx.x >> 6, l = threadIdx.x & 63;
    int n = blockIdx.x;             // grid = exactly N_NODES blocks

    float4 qv = ((const float4*)(qbuf + (size_t)n * 256))[l];  // dims 4l..4l+3, head = l>>4
    int beg = offs[n], end = offs[n + 1];

    float4 acc = make_float4(0.f, 0.f, 0.f, 0.f);
    float den = 0.f;

    for (int base = beg; base < end; base += 256) {
        int m = end - base; if (m > 256) m = 256;
        int eIdx = w + 4 * l;                         // this wave+lane's edge slot
        int mysrc = (eIdx < m) ? ssrc[base + eIdx] : 0;
        int nIter = (m > w) ? ((m - w + 3) >> 2) : 0; // edges w, w+4, ... < m
        for (int jj = 0; jj < nIter; jj++) {
            int src = __shfl(mysrc, jj, 64);
            const unsigned short* row = kvb + (size_t)src * 512;
            ushort4 ku = ((const ushort4*)row)[l];          // k dims 4l..4l+3
            ushort4 vu = ((const ushort4*)(row + 256))[l];  // v dims 4l..4l+3
            float p = qv.x * bf2f(ku.x) + qv.y * bf2f(ku.y) +
                      qv.z * bf2f(ku.z) + qv.w * bf2f(ku.w);
            p += __shfl_xor(p, 1, 16);
            p += __shfl_xor(p, 2, 16);
            p += __shfl_xor(p, 4, 16);
            p += __shfl_xor(p, 8, 16);           // all 16 lanes of a head hold s
            float ex = expf(p * 0.125f);
            den += ex;
            acc.x += ex * bf2f(vu.x); acc.y += ex * bf2f(vu.y);
            acc.z += ex * bf2f(vu.z); acc.w += ex * bf2f(vu.w);
        }
    }

    lacc[w][l] = acc;
    lden[w][l] = den;
    __syncthreads();
    if (w != 0) return;

    float4 a0 = lacc[0][l], a1 = lacc[1][l], a2 = lacc[2][l], a3 = lacc[3][l];
    acc.x = a0.x + a1.x + a2.x + a3.x;
    acc.y = a0.y + a1.y + a2.y + a3.y;
    acc.z = a0.z + a1.z + a2.z + a3.z;
    acc.w = a0.w + a1.w + a2.w + a3.w;
    den = lden[0][l] + lden[1][l] + lden[2][l] + lden[3][l];

    float inv = (den > 0.f) ? 1.f / den : 0.f;     // deg-0 node -> agg = 0 (matches ref)
    float4 sk = ((const float4*)(sbuf + (size_t)n * 256))[l];

    float z0 = acc.x * inv + sk.x;
    float z1 = acc.y * inv + sk.y;
    float z2 = acc.z * inv + sk.z;
    float z3 = acc.w * inv + sk.w;

    const float is2 = 0.70710678118f;
    float h0 = 0.5f * z0 * (1.f + erff(z0 * is2));
    float h1 = 0.5f * z1 * (1.f + erff(z1 * is2));
    float h2 = 0.5f * z2 * (1.f + erff(z2 * is2));
    float h3 = 0.5f * z3 * (1.f + erff(z3 * is2));
    ((float4*)(out_h + (size_t)n * 256))[l] = make_float4(h0, h1, h2, h3);

    int d0 = l * 4;
    float s0 = h0 * gate_w[(d0 + 0) * 2] + h1 * gate_w[(d0 + 1) * 2] +
               h2 * gate_w[(d0 + 2) * 2] + h3 * gate_w[(d0 + 3) * 2];
    float s1 = h0 * gate_w[(d0 + 0) * 2 + 1] + h1 * gate_w[(d0 + 1) * 2 + 1] +
               h2 * gate_w[(d0 + 2) * 2 + 1] + h3 * gate_w[(d0 + 3) * 2 + 1];
#pragma unroll
    for (int off = 1; off < 64; off <<= 1) {
        s0 += __shfl_xor(s0, off, 64);
        s1 += __shfl_xor(s1, off, 64);
    }
    if (l == 0) {
        exsc[n * 2 + 0] = expf(s0 + gate_b[0]);
        exsc[n * 2 + 1] = expf(s1 + gate_b[1]);
    }
}

// ---------------- esum[c] = sum_n exsc[n,c] ----------------
__global__ void k_esum(const float* __restrict__ exsc, float* __restrict__ esum) {
    __shared__ float red0[4], red1[4];
    float p0 = 0.f, p1 = 0.f;
    for (int n = blockIdx.x * blockDim.x + threadIdx.x; n < N_NODES; n += gridDim.x * blockDim.x) {
        p0 += exsc[n * 2];
        p1 += exsc[n * 2 + 1];
    }
#pragma unroll
    for (int off = 1; off < 64; off <<= 1) {
        p0 += __shfl_xor(p0, off, 64);
        p1 += __shfl_xor(p1, off, 64);
    }
    int w = threadIdx.x >> 6, l = threadIdx.x & 63;
    if (l == 0) { red0[w] = p0; red1[w] = p1; }
    __syncthreads();
    if (threadIdx.x == 0) {
        atomicAdd(&esum[0], red0[0] + red0[1] + red0[2] + red0[3]);
        atomicAdd(&esum[1], red1[0] + red1[1] + red1[2] + red1[3]);
    }
}

// ---------------- attn/A outputs (fp32) + t[c,d] = sum_n attn[n,c] h[n,d] ----------------
__global__ void k_t(const float* __restrict__ exsc, const float* __restrict__ esum,
                    const float* __restrict__ h_f, const int* __restrict__ label_p,
                    float* __restrict__ attn_out, float* __restrict__ A_out,
                    float* __restrict__ t_ws) {
    int d = threadIdx.x;
    float inv0 = 1.f / esum[0], inv1 = 1.f / esum[1];
    int lab = *label_p;
    int n0 = blockIdx.x * 98;
    int n1 = n0 + 98; if (n1 > N_NODES) n1 = N_NODES;
    float t0 = 0.f, t1 = 0.f;
    for (int n = n0; n < n1; n++) {
        float e0 = exsc[n * 2], e1 = exsc[n * 2 + 1];
        float a0 = e0 * inv0, a1 = e1 * inv1;
        float hv = h_f[(size_t)n * 256 + d];
        t0 += a0 * hv;
        t1 += a1 * hv;
        if (d == 0) attn_out[n * 2] = a0;
        else if (d == 1) attn_out[n * 2 + 1] = a1;
        else if (d == 2) A_out[n] = (lab == 0) ? a0 : a1;
    }
    atomicAdd(&t_ws[d], t0);
    atomicAdd(&t_ws[256 + d], t1);
}

// ---------------- y = t @ pool_w + pool_b (fp32 out) ----------------
__global__ void k_y(const float* __restrict__ t_ws, const float* __restrict__ pool_w,
                    const float* __restrict__ pool_b, float* __restrict__ y_out) {
    int d = threadIdx.x;
    float a0 = pool_b[d], a1 = pool_b[d];
    for (int k = 0; k < 256; k++) {
        float w = pool_w[k * 256 + d];
        a0 += t_ws[k] * w;
        a1 += t_ws[256 + k] * w;
    }
    y_out[d] = a0;
    y_out[256 + d] = a1;
}

extern "C" void kernel_launch(void* const* d_in, const int* in_sizes, int n_in,
                              void* d_out, int out_size, void* d_ws, size_t ws_size,
                              hipStream_t stream) {
    const float* x      = (const float*)d_in[0];
    const int*   ei     = (const int*)d_in[1];
    const int*   label  = (const int*)d_in[2];
    const float* Wq     = (const float*)d_in[3];
    const float* bq     = (const float*)d_in[4];
    const float* Wk     = (const float*)d_in[5];
    const float* bk     = (const float*)d_in[6];
    const float* Wv     = (const float*)d_in[7];
    const float* bv     = (const float*)d_in[8];
    const float* Wskip  = (const float*)d_in[9];
    const float* bskip  = (const float*)d_in[10];
    const float* gate_w = (const float*)d_in[11];
    const float* gate_b = (const float*)d_in[12];
    const float* pool_w = (const float*)d_in[13];
    const float* pool_b = (const float*)d_in[14];

    char* ws = (char*)d_ws;
    size_t off = 0;
    float* qbuf = (float*)(ws + off);                 off += (size_t)M_PAD * 256 * 4;    // 51.25 MB
    unsigned short* kvb = (unsigned short*)(ws + off);off += (size_t)M_PAD * 512 * 2;    // 51.25 MB
    float* sbuf = (float*)(ws + off);                 off += (size_t)M_PAD * 256 * 4;    // 51.25 MB
    unsigned short* xb = (unsigned short*)(ws + off); off += (size_t)M_PAD * 1024 * 2;   // 102.5 MB
    unsigned short* WT = (unsigned short*)(ws + off); off += (size_t)1024 * 1024 * 2;    // 2 MB
    float* biascat = (float*)(ws + off);              off += 1024 * 4;
    int* cnt  = (int*)(ws + off);                     off += (size_t)N_NODES * 4;        // 200 KB
    int* fill = (int*)(ws + off);                     off += (size_t)N_NODES * 4;        // 200 KB (contig w/ cnt)
    int* offs = (int*)(ws + off);                     off += (size_t)(N_NODES + 1) * 4;
    int* ssrc = (int*)(ws + off);                     off += (size_t)N_EDGES * 4;        // 1.6 MB
    float* exsc = (float*)(ws + off);                 off += (size_t)N_NODES * 2 * 4;    // 0.4 MB
    float* esum = (float*)(ws + off);                 off += 2 * 4;
    float* t_ws = (float*)(ws + off);                 off += 512 * 4;

    // Outputs are FP32, concatenated flat in return order.
    float* out = (float*)d_out;
    float* y_out    = out;                 // 512
    float* attn_out = out + 512;           // 100000
    float* h_out    = out + 100512;        // 12800000
    float* A_out    = out + 12900512;      // 50000

    // zero cnt+fill (contiguous) and esum+t_ws (contiguous)
    hipMemsetAsync(cnt, 0, (size_t)N_NODES * 2 * 4, stream);
    hipMemsetAsync(esum, 0, (2 + 512) * 4, stream);

    // fused: conv_x (blocks 0..4095) | build_w (4096..8191) | hist (8192..9754)
    k_pre<<<9755, 256, 0, stream>>>(x, xb, Wq, Wk, Wv, Wskip, bq, bk, bv, bskip,
                                    WT, biascat, ei, cnt);
    k_scan<<<1, 256, 0, stream>>>(cnt, offs);
    // GEMM blocks 0..3135 (8 xcd * 392, yt-guard) + scatter blocks 3136..4698
    k_gemm<<<4699, 256, 0, stream>>>(xb, WT, biascat, qbuf, kvb, sbuf,
                                     ei, offs, fill, ssrc);
    k_attn<<<N_NODES, 256, 0, stream>>>(offs, ssrc, qbuf, kvb, sbuf, gate_w, gate_b,
                                        h_out, exsc);
    k_esum<<<128, 256, 0, stream>>>(exsc, esum);
    k_t<<<512, 256, 0, stream>>>(exsc, esum, h_out, label, attn_out, A_out, t_ws);
    k_y<<<1, 256, 0, stream>>>(t_ws, pool_w, pool_b, y_out);
}